// Round 8
// baseline (710.468 us; speedup 1.0000x reference)
//
#include <hip/hip_runtime.h>
#include <hip/hip_bf16.h>
#include <stdint.h>

namespace {
constexpr int kB = 4, kT = 2048, kC = 1024, kH = 16, kD = 64;
constexpr int kM = kB * kT;        // 8192
constexpr int kR = 8;
constexpr float kScaling = 4.0f;   // ALPHA / R
// softmax scale folded with log2(e) so attention can use exp2 directly
constexpr float kQScale = 0.125f * 1.4426950408889634f;
}

typedef short short8 __attribute__((ext_vector_type(8)));
typedef float f32x4 __attribute__((ext_vector_type(4)));
typedef unsigned short ushort4v __attribute__((ext_vector_type(4)));
typedef unsigned short ushort8v __attribute__((ext_vector_type(8)));
typedef unsigned int uint2v __attribute__((ext_vector_type(2)));

// ---------------------------------------------------------------------------
// bf16 helpers (HW cvt path: __float2bfloat16 -> v_cvt_*_bf16_f32)
// ---------------------------------------------------------------------------
__device__ inline unsigned short bf16_bits(float f) {
  __hip_bfloat16 h = __float2bfloat16(f);
  unsigned short u;
  __builtin_memcpy(&u, &h, 2);
  return u;
}
__device__ inline float bits_f(unsigned short u) {
  return __uint_as_float((uint32_t)u << 16);
}
__device__ inline void split1(float f, unsigned short& h, unsigned short& l) {
  h = bf16_bits(f);
  l = bf16_bits(f - bits_f(h));
}
__device__ inline uint32_t cvtpk2(float a, float b) {
  __hip_bfloat162 h2 = __float22bfloat162_rn(float2{a, b});
  uint32_t u;
  __builtin_memcpy(&u, &h2, 4);
  return u;
}

// ---------------------------------------------------------------------------
// Kernel 0: pack fp32 -> bf16 hi/lo planes (grid-stride, memory-bound).
// ---------------------------------------------------------------------------
__global__ __launch_bounds__(256) void pack_kernel(
    const float* __restrict__ s, unsigned short* __restrict__ hp,
    unsigned short* __restrict__ lp, int n4) {
  int i = blockIdx.x * 256 + threadIdx.x;
  const int stride = gridDim.x * 256;
  for (; i < n4; i += stride) {
    const float4 v = reinterpret_cast<const float4*>(s)[i];
    const float f[4] = {v.x, v.y, v.z, v.w};
    ushort4v h, l;
#pragma unroll
    for (int j = 0; j < 4; ++j) {
      unsigned short hb, lb;
      split1(f[j], hb, lb);
      h[j] = hb;
      l[j] = lb;
    }
    reinterpret_cast<ushort4v*>(hp)[i] = h;
    reinterpret_cast<ushort4v*>(lp)[i] = l;
  }
}

// ---------------------------------------------------------------------------
// Kernel 1: XA[m][0..7] = x[m]·Aq[r][:],  XA[m][8..15] = x[m]·Av[r][:]
// ---------------------------------------------------------------------------
__global__ __launch_bounds__(256) void lora_xa_kernel(
    const float* __restrict__ x, const float* __restrict__ Aq,
    const float* __restrict__ Av, float* __restrict__ xa) {
  const int wave = threadIdx.x >> 6;
  const int lane = threadIdx.x & 63;
  const int row = (blockIdx.x << 2) + wave;
  const float4* xr = reinterpret_cast<const float4*>(x) + (size_t)row * (kC / 4);
  const float4* aq = reinterpret_cast<const float4*>(Aq);
  const float4* av = reinterpret_cast<const float4*>(Av);
  float acc[16];
#pragma unroll
  for (int r = 0; r < 16; ++r) acc[r] = 0.f;
#pragma unroll
  for (int jj = 0; jj < (kC / 4) / 64; ++jj) {
    const int j = lane + jj * 64;
    const float4 xv = xr[j];
#pragma unroll
    for (int r = 0; r < 8; ++r) {
      const float4 a = aq[r * (kC / 4) + j];
      acc[r] += xv.x * a.x + xv.y * a.y + xv.z * a.z + xv.w * a.w;
      const float4 b = av[r * (kC / 4) + j];
      acc[8 + r] += xv.x * b.x + xv.y * b.y + xv.z * b.z + xv.w * b.w;
    }
  }
#pragma unroll
  for (int r = 0; r < 16; ++r) {
    float v = acc[r];
#pragma unroll
    for (int off = 32; off > 0; off >>= 1) v += __shfl_xor(v, off, 64);
    if (lane == 0) xa[(size_t)row * 16 + r] = v;
  }
}

// ---------------------------------------------------------------------------
// Kernel 2: plane-input bf16x3 MFMA GEMM.
//   A = Ah+Al (bf16 hi/lo planes, [M][K]); B = Bh+Bl ([N][K]).
//   out = (A·B^T + bias (+ LoRA)) * out_scale
// 128x128 tile, BK=32, 4 waves (2x2 of 64x64), 16x16x32 bf16 MFMA, x3.
// LDS rows 128B: chunks 0-3 hi / 4-7 lo, chunk XOR (row&7) (T2). Staging is
// pure 16B copies (planes pre-split) with next-K-tile reg prefetch (T14).
// out_mode: 0 fp32 [M][C] (o32); 1 dual bf16 planes [B,H,T,D] (o16a/o16b);
//           2 single bf16 plane [B,H,D,T] (o16a).
// ---------------------------------------------------------------------------
__global__ __launch_bounds__(256, 2) void gemm_planes_kernel(
    const unsigned short* __restrict__ Ah_g, const unsigned short* __restrict__ Al_g,
    const unsigned short* __restrict__ Bh_g, const unsigned short* __restrict__ Bl_g,
    const float* __restrict__ bias, const float* __restrict__ xa,
    const float* __restrict__ Bm,
    unsigned short* __restrict__ o16a, unsigned short* __restrict__ o16b,
    float* __restrict__ o32,
    const int lora_sel, const int out_mode, const float out_scale) {
  constexpr int BK = 32;
  __shared__ __align__(16) unsigned char sA[128 * 128];
  __shared__ __align__(16) unsigned char sB[128 * 128];

  const int tid = threadIdx.x;
  const int m0 = blockIdx.y << 7;
  const int n0 = blockIdx.x << 7;
  const int wave = tid >> 6, lane = tid & 63;
  const int wr = wave >> 1, wc = wave & 1;
  const int lrow = lane & 15;
  const int lkg = lane >> 4;

  // Staging: thread -> row srow (0..127), chunk pair sc0,sc0+1 (16B chunks).
  const int srow = tid >> 1;
  const int sc0 = (tid & 1) << 1;
  const unsigned short* pa_h = Ah_g + (size_t)(m0 + srow) * kC + sc0 * 8;
  const unsigned short* pa_l = Al_g + (size_t)(m0 + srow) * kC + sc0 * 8;
  const unsigned short* pb_h = Bh_g + (size_t)(n0 + srow) * kC + sc0 * 8;
  const unsigned short* pb_l = Bl_g + (size_t)(n0 + srow) * kC + sc0 * 8;

  f32x4 acc[4][4];
#pragma unroll
  for (int a = 0; a < 4; ++a)
#pragma unroll
    for (int b = 0; b < 4; ++b) acc[a][b] = (f32x4){0.f, 0.f, 0.f, 0.f};

  ushort8v rah[2], ral[2], rbh[2], rbl[2];
#pragma unroll
  for (int j = 0; j < 2; ++j) {
    rah[j] = *reinterpret_cast<const ushort8v*>(pa_h + j * 8);
    ral[j] = *reinterpret_cast<const ushort8v*>(pa_l + j * 8);
    rbh[j] = *reinterpret_cast<const ushort8v*>(pb_h + j * 8);
    rbl[j] = *reinterpret_cast<const ushort8v*>(pb_l + j * 8);
  }

  for (int k0 = 0; k0 < kC; k0 += BK) {
    const int rbase = srow * 128;
    const int s7 = srow & 7;
#pragma unroll
    for (int j = 0; j < 2; ++j) {
      const int c = sc0 + j;
      *reinterpret_cast<ushort8v*>(&sA[rbase + ((c ^ s7) << 4)]) = rah[j];
      *reinterpret_cast<ushort8v*>(&sA[rbase + (((c | 4) ^ s7) << 4)]) = ral[j];
      *reinterpret_cast<ushort8v*>(&sB[rbase + ((c ^ s7) << 4)]) = rbh[j];
      *reinterpret_cast<ushort8v*>(&sB[rbase + (((c | 4) ^ s7) << 4)]) = rbl[j];
    }
    __syncthreads();

    if (k0 + BK < kC) {
      const int kn = k0 + BK;
#pragma unroll
      for (int j = 0; j < 2; ++j) {
        rah[j] = *reinterpret_cast<const ushort8v*>(pa_h + kn + j * 8);
        ral[j] = *reinterpret_cast<const ushort8v*>(pa_l + kn + j * 8);
        rbh[j] = *reinterpret_cast<const ushort8v*>(pb_h + kn + j * 8);
        rbl[j] = *reinterpret_cast<const ushort8v*>(pb_l + kn + j * 8);
      }
    }

    short8 ah[4], al[4];
#pragma unroll
    for (int rb = 0; rb < 4; ++rb) {
      const int rA = wr * 64 + rb * 16 + lrow;
      ah[rb] = *reinterpret_cast<const short8*>(&sA[rA * 128 + ((lkg ^ (rA & 7)) << 4)]);
      al[rb] = *reinterpret_cast<const short8*>(&sA[rA * 128 + (((lkg | 4) ^ (rA & 7)) << 4)]);
    }
#pragma unroll
    for (int cb = 0; cb < 4; ++cb) {
      const int rB = wc * 64 + cb * 16 + lrow;
      const short8 bhf = *reinterpret_cast<const short8*>(&sB[rB * 128 + ((lkg ^ (rB & 7)) << 4)]);
      const short8 blf = *reinterpret_cast<const short8*>(&sB[rB * 128 + (((lkg | 4) ^ (rB & 7)) << 4)]);
#pragma unroll
      for (int rb = 0; rb < 4; ++rb) {
        acc[rb][cb] = __builtin_amdgcn_mfma_f32_16x16x32_bf16(ah[rb], bhf, acc[rb][cb], 0, 0, 0);
        acc[rb][cb] = __builtin_amdgcn_mfma_f32_16x16x32_bf16(ah[rb], blf, acc[rb][cb], 0, 0, 0);
        acc[rb][cb] = __builtin_amdgcn_mfma_f32_16x16x32_bf16(al[rb], bhf, acc[rb][cb], 0, 0, 0);
      }
    }
    __syncthreads();
  }

  // Epilogue: bias (+ LoRA), scale, store per out_mode.
#pragma unroll
  for (int rb = 0; rb < 4; ++rb) {
    const int mbase = m0 + wr * 64 + rb * 16 + (lkg << 2);
    float la2[4][kR];
    if (lora_sel >= 0) {
#pragma unroll
      for (int i = 0; i < 4; ++i)
#pragma unroll
        for (int r = 0; r < kR; ++r)
          la2[i][r] = xa[(size_t)(mbase + i) * 16 + lora_sel + r];
    }
#pragma unroll
    for (int cb = 0; cb < 4; ++cb) {
      const int n = n0 + wc * 64 + cb * 16 + lrow;
      const float bi = bias[n];
      float vv[4];
#pragma unroll
      for (int i = 0; i < 4; ++i) {
        vv[i] = acc[rb][cb][i] + bi;
        if (lora_sel >= 0) {
          float lv = 0.f;
#pragma unroll
          for (int r = 0; r < kR; ++r)
            lv = fmaf(la2[i][r], Bm[(size_t)n * kR + r], lv);
          vv[i] += kScaling * lv;
        }
        vv[i] *= out_scale;
      }
      if (out_mode == 1) {
        const int bb_ = mbase >> 11;
        const int t0 = mbase & (kT - 1);
        const int hh = n >> 6;
        const int dd = n & (kD - 1);
#pragma unroll
        for (int i = 0; i < 4; ++i) {
          const size_t off = (((size_t)bb_ * kH + hh) * kT + t0 + i) * kD + dd;
          unsigned short hb, lb;
          split1(vv[i], hb, lb);
          o16a[off] = hb;
          o16b[off] = lb;
        }
      } else if (out_mode == 2) {
        const int bb_ = mbase >> 11;
        const int t0 = mbase & (kT - 1);
        const int hh = n >> 6;
        const int dd = n & (kD - 1);
        ushort4v w;
#pragma unroll
        for (int i = 0; i < 4; ++i) w[i] = bf16_bits(vv[i]);
        *reinterpret_cast<ushort4v*>(
            o16a + (((size_t)bb_ * kH + hh) * kD + dd) * kT + t0) = w;
      } else {
#pragma unroll
        for (int i = 0; i < 4; ++i)
          o32[(size_t)(mbase + i) * kC + n] = vv[i];
      }
    }
  }
}

// ---------------------------------------------------------------------------
// Kernel 3: flash attention, bf16 MFMA, QBLK=128, KVBLK=64. All inputs are
// pre-split bf16 planes (Qh/Ql scaled by log2e/8) -> staging is byte-copy
// only; softmax in log2 domain (exp2 = bare v_exp_f32); P-cvt via cvt_pk.
// Outputs ctx as bf16 hi/lo planes [B,T,C] for the plane-input O-proj.
// ---------------------------------------------------------------------------
__global__ __launch_bounds__(256) void attn_mfma_kernel(
    const unsigned short* __restrict__ Qh, const unsigned short* __restrict__ Ql,
    const unsigned short* __restrict__ Kh_g, const unsigned short* __restrict__ Kl_g,
    const unsigned short* __restrict__ Vt_g,
    unsigned short* __restrict__ ctx_h, unsigned short* __restrict__ ctx_l) {
  __shared__ __align__(16) unsigned char sKh[64 * 128];
  __shared__ __align__(16) unsigned char sKl[64 * 128];
  __shared__ __align__(16) unsigned char sVt[64 * 128];
  __shared__ __align__(16) unsigned char sP[128 * 128];

  const int tid = threadIdx.x;
  const int wave = tid >> 6, lane = tid & 63;
  const int lrow = lane & 15, lg = lane >> 4;
  const int bh = blockIdx.y;
  const int q0 = blockIdx.x << 7;
  const int b = bh >> 4, h = bh & 15;

  // ---- Q fragments direct from planes (already scaled).
  short8 qh[2][2], ql[2][2];
#pragma unroll
  for (int qs = 0; qs < 2; ++qs)
#pragma unroll
    for (int d0 = 0; d0 < 2; ++d0) {
      const size_t off =
          ((size_t)bh * kT + q0 + wave * 32 + qs * 16 + lrow) * kD + d0 * 32 + lg * 8;
      qh[qs][d0] = *reinterpret_cast<const short8*>(Qh + off);
      ql[qs][d0] = *reinterpret_cast<const short8*>(Ql + off);
    }

  // Staging: thread -> row srow (0..63), chunk pair sc0,sc0+1.
  const int srow = tid >> 2;
  const int sc0 = (tid & 3) << 1;
  const unsigned short* khs = Kh_g + ((size_t)bh * kT + srow) * kD + sc0 * 8;
  const unsigned short* kls = Kl_g + ((size_t)bh * kT + srow) * kD + sc0 * 8;
  const unsigned short* vts = Vt_g + ((size_t)bh * kD + srow) * kT + sc0 * 8;

  f32x4 acc_o[2][4];
#pragma unroll
  for (int qs = 0; qs < 2; ++qs)
#pragma unroll
    for (int dr = 0; dr < 4; ++dr) acc_o[qs][dr] = (f32x4){0.f, 0.f, 0.f, 0.f};
  float m_i[2] = {-3.0e38f, -3.0e38f};
  float l_i[2] = {0.f, 0.f};

  constexpr int kNT = kT / 64;
  ushort8v kph[2], kpl[2], vpv[2];
#pragma unroll
  for (int j = 0; j < 2; ++j) {
    kph[j] = *reinterpret_cast<const ushort8v*>(khs + j * 8);
    kpl[j] = *reinterpret_cast<const ushort8v*>(kls + j * 8);
    vpv[j] = *reinterpret_cast<const ushort8v*>(vts + j * 8);
  }

  for (int kt = 0; kt < kNT; ++kt) {
    // ---- Byte-copy staged tile into swizzled LDS.
    {
      const int rb2 = srow * 128;
      const int s7 = srow & 7;
#pragma unroll
      for (int j = 0; j < 2; ++j) {
        const int c = sc0 + j;
        *reinterpret_cast<ushort8v*>(&sKh[rb2 + ((c ^ s7) << 4)]) = kph[j];
        *reinterpret_cast<ushort8v*>(&sKl[rb2 + ((c ^ s7) << 4)]) = kpl[j];
        *reinterpret_cast<ushort8v*>(&sVt[rb2 + ((c ^ s7) << 4)]) = vpv[j];
      }
    }
    __syncthreads();

    // ---- Issue next tile's loads (hidden under MFMA).
    if (kt + 1 < kNT) {
      const size_t koffK = (size_t)(kt + 1) * 64 * kD;
      const int koffV = (kt + 1) * 64;
#pragma unroll
      for (int j = 0; j < 2; ++j) {
        kph[j] = *reinterpret_cast<const ushort8v*>(khs + koffK + j * 8);
        kpl[j] = *reinterpret_cast<const ushort8v*>(kls + koffK + j * 8);
        vpv[j] = *reinterpret_cast<const ushort8v*>(vts + koffV + j * 8);
      }
    }

    // ---- S = K·Q^T (x3): lane = S[kv=16kvr+4lg+i][q=lrow], log2-scaled.
    f32x4 acc_s[2][4];
#pragma unroll
    for (int qs = 0; qs < 2; ++qs)
#pragma unroll
      for (int kvr = 0; kvr < 4; ++kvr) acc_s[qs][kvr] = (f32x4){0.f, 0.f, 0.f, 0.f};
#pragma unroll
    for (int d0 = 0; d0 < 2; ++d0) {
#pragma unroll
      for (int kvr = 0; kvr < 4; ++kvr) {
        const int rk = kvr * 16 + lrow;
        const int byt = rk * 128 + ((((d0 << 2) + lg) ^ (rk & 7)) << 4);
        const short8 khf = *reinterpret_cast<const short8*>(&sKh[byt]);
        const short8 klf = *reinterpret_cast<const short8*>(&sKl[byt]);
#pragma unroll
        for (int qs = 0; qs < 2; ++qs) {
          acc_s[qs][kvr] = __builtin_amdgcn_mfma_f32_16x16x32_bf16(khf, qh[qs][d0], acc_s[qs][kvr], 0, 0, 0);
          acc_s[qs][kvr] = __builtin_amdgcn_mfma_f32_16x16x32_bf16(khf, ql[qs][d0], acc_s[qs][kvr], 0, 0, 0);
          acc_s[qs][kvr] = __builtin_amdgcn_mfma_f32_16x16x32_bf16(klf, qh[qs][d0], acc_s[qs][kvr], 0, 0, 0);
        }
      }
    }

    // ---- Online softmax (log2 domain) per q-subtile.
#pragma unroll
    for (int qs = 0; qs < 2; ++qs) {
      float mx = acc_s[qs][0][0];
#pragma unroll
      for (int kvr = 0; kvr < 4; ++kvr)
#pragma unroll
        for (int i = 0; i < 4; ++i) mx = fmaxf(mx, acc_s[qs][kvr][i]);
      mx = fmaxf(mx, __shfl_xor(mx, 16, 64));
      mx = fmaxf(mx, __shfl_xor(mx, 32, 64));
      const float mnew = fmaxf(m_i[qs], mx);
      const float alpha = __builtin_exp2f(m_i[qs] - mnew);
      m_i[qs] = mnew;
      const int prow = wave * 32 + qs * 16 + lrow;
      const int p7 = prow & 7;
      float rs = 0.f;
#pragma unroll
      for (int kvr = 0; kvr < 4; ++kvr) {
        float p[4];
#pragma unroll
        for (int i = 0; i < 4; ++i) {
          p[i] = __builtin_exp2f(acc_s[qs][kvr][i] - mnew);
          rs += p[i];
        }
        uint2v pu;
        pu[0] = cvtpk2(p[0], p[1]);
        pu[1] = cvtpk2(p[2], p[3]);
        const int chunk = ((kvr << 1) + (lg >> 1)) ^ p7;
        *reinterpret_cast<uint2v*>(&sP[prow * 128 + (chunk << 4) + ((lg & 1) << 3)]) = pu;
      }
      rs += __shfl_xor(rs, 16, 64);
      rs += __shfl_xor(rs, 32, 64);
      l_i[qs] = l_i[qs] * alpha + rs;
#pragma unroll
      for (int dr = 0; dr < 4; ++dr)
#pragma unroll
        for (int i = 0; i < 4; ++i) acc_o[qs][dr][i] *= alpha;
    }
    __builtin_amdgcn_sched_barrier(0);  // P writes precede P reads (same wave)

    // ---- O^T += Vt·P^T.
#pragma unroll
    for (int ks = 0; ks < 2; ++ks) {
      short8 pf[2];
#pragma unroll
      for (int qs = 0; qs < 2; ++qs) {
        const int prow = wave * 32 + qs * 16 + lrow;
        pf[qs] = *reinterpret_cast<const short8*>(
            &sP[prow * 128 + ((((ks << 2) + lg) ^ (prow & 7)) << 4)]);
      }
#pragma unroll
      for (int dr = 0; dr < 4; ++dr) {
        const int rv = dr * 16 + lrow;
        const short8 vf = *reinterpret_cast<const short8*>(
            &sVt[rv * 128 + ((((ks << 2) + lg) ^ (rv & 7)) << 4)]);
        acc_o[0][dr] = __builtin_amdgcn_mfma_f32_16x16x32_bf16(vf, pf[0], acc_o[0][dr], 0, 0, 0);
        acc_o[1][dr] = __builtin_amdgcn_mfma_f32_16x16x32_bf16(vf, pf[1], acc_o[1][dr], 0, 0, 0);
      }
    }
    __syncthreads();
  }

  // ---- Epilogue: O/l -> ctx hi/lo bf16 planes [B,T,C], C = h*64 + d.
#pragma unroll
  for (int qs = 0; qs < 2; ++qs) {
    const float inv = 1.0f / l_i[qs];
    const int qq = q0 + wave * 32 + qs * 16 + lrow;
    const size_t base = ((size_t)b * kT + qq) * kC + (h << 6);
#pragma unroll
    for (int dr = 0; dr < 4; ++dr) {
      ushort4v wh, wl;
#pragma unroll
      for (int i = 0; i < 4; ++i) {
        unsigned short hb, lb;
        split1(acc_o[qs][dr][i] * inv, hb, lb);
        wh[i] = hb;
        wl[i] = lb;
      }
      *reinterpret_cast<ushort4v*>(ctx_h + base + dr * 16 + (lg << 2)) = wh;
      *reinterpret_cast<ushort4v*>(ctx_l + base + dr * 16 + (lg << 2)) = wl;
    }
  }
}

// ---------------------------------------------------------------------------
extern "C" void kernel_launch(void* const* d_in, const int* in_sizes, int n_in,
                              void* d_out, int out_size, void* d_ws, size_t ws_size,
                              hipStream_t stream) {
  const float* x  = (const float*)d_in[0];
  const float* Wq = (const float*)d_in[1];
  const float* bq = (const float*)d_in[2];
  const float* Wk = (const float*)d_in[3];
  const float* bk = (const float*)d_in[4];
  const float* Wv = (const float*)d_in[5];
  const float* bv = (const float*)d_in[6];
  const float* Wo = (const float*)d_in[7];
  const float* bo = (const float*)d_in[8];
  const float* Aq = (const float*)d_in[9];
  const float* Bq = (const float*)d_in[10];
  const float* Av = (const float*)d_in[11];
  const float* Bv = (const float*)d_in[12];
  float* out = (float*)d_out;

  constexpr size_t MP = (size_t)kM * kC;   // 8M elements
  constexpr size_t WP = (size_t)kC * kC;   // 1M elements
  unsigned short* w16 = (unsigned short*)d_ws;
  unsigned short* Xh  = w16;            // also ctx_h (aliased after V-GEMM)
  unsigned short* Xl  = Xh  + MP;       // also ctx_l
  unsigned short* Wqh = Xl  + MP;
  unsigned short* Wql = Wqh + WP;
  unsigned short* Wkh = Wql + WP;
  unsigned short* Wkl = Wkh + WP;
  unsigned short* Wvh = Wkl + WP;
  unsigned short* Wvl = Wvh + WP;
  unsigned short* Woh = Wvl + WP;
  unsigned short* Wol = Woh + WP;
  unsigned short* Qh  = Wol + WP;
  unsigned short* Ql  = Qh  + MP;
  unsigned short* Kh  = Ql  + MP;
  unsigned short* Kl  = Kh  + MP;
  unsigned short* Vt  = Kl  + MP;
  float* xa = (float*)(Vt + MP);        // [M,16]

  // 0) pack fp32 -> bf16 hi/lo planes
  hipLaunchKernelGGL(pack_kernel, dim3(2048), dim3(256), 0, stream, x, Xh, Xl, (int)(MP / 4));
  hipLaunchKernelGGL(pack_kernel, dim3(1024), dim3(256), 0, stream, Wq, Wqh, Wql, (int)(WP / 4));
  hipLaunchKernelGGL(pack_kernel, dim3(1024), dim3(256), 0, stream, Wk, Wkh, Wkl, (int)(WP / 4));
  hipLaunchKernelGGL(pack_kernel, dim3(1024), dim3(256), 0, stream, Wv, Wvh, Wvl, (int)(WP / 4));
  hipLaunchKernelGGL(pack_kernel, dim3(1024), dim3(256), 0, stream, Wo, Woh, Wol, (int)(WP / 4));

  // 1) LoRA down-projections
  hipLaunchKernelGGL(lora_xa_kernel, dim3(kM / 4), dim3(256), 0, stream, x, Aq, Av, xa);

  // 2) Q/K/V projections -> bf16 planes (Q scaled by log2e/8; V transposed)
  const dim3 gg(kC / 128, kM / 128);
  hipLaunchKernelGGL(gemm_planes_kernel, gg, dim3(256), 0, stream,
                     Xh, Xl, Wqh, Wql, bq, xa, Bq, Qh, Ql, nullptr, 0, 1, kQScale);
  hipLaunchKernelGGL(gemm_planes_kernel, gg, dim3(256), 0, stream,
                     Xh, Xl, Wkh, Wkl, bk, nullptr, nullptr, Kh, Kl, nullptr, -1, 1, 1.0f);
  hipLaunchKernelGGL(gemm_planes_kernel, gg, dim3(256), 0, stream,
                     Xh, Xl, Wvh, Wvl, bv, xa, Bv, Vt, nullptr, nullptr, 8, 2, 1.0f);

  // 3) Attention (writes ctx planes over the dead X planes)
  hipLaunchKernelGGL(attn_mfma_kernel, dim3(kT / 128, kB * kH), dim3(256), 0, stream,
                     Qh, Ql, Kh, Kl, Vt, Xh, Xl);

  // 4) Output projection -> d_out (fp32 [B,T,C])
  hipLaunchKernelGGL(gemm_planes_kernel, gg, dim3(256), 0, stream,
                     Xh, Xl, Woh, Wol, bo, nullptr, nullptr, nullptr, nullptr, out, -1, 0, 1.0f);
}